// Round 1
// baseline (333.415 us; speedup 1.0000x reference)
//
#include <hip/hip_runtime.h>
#include <math.h>

#define N 2048
#define F 128
#define O 128
#define E 16

// Kernel 1: pre[b][n][o] = sum_k x[n][k] * w_b[k][o]   (b = 0,1)
__global__ __launch_bounds__(128)
void pre_gemm(const float* __restrict__ x,
              const float* __restrict__ w0,
              const float* __restrict__ w1,
              float* __restrict__ pre) {
    const int n = blockIdx.x;
    const int b = blockIdx.y;
    const int o = threadIdx.x;
    const float* __restrict__ w = b ? w1 : w0;
    __shared__ float xs[F];
    xs[o] = x[(size_t)n * F + o];
    __syncthreads();
    float acc = 0.f;
#pragma unroll 8
    for (int k = 0; k < F; ++k)
        acc += xs[k] * w[(size_t)k * O + o];
    pre[(size_t)b * N * O + (size_t)n * O + o] = acc;
}

// Kernel 2: G[n,m] = sigmoid(dot16(ef[n,m,:], we[n,m,:]) + be[n,m]) * sup1[n,m]
// 4 lanes cooperate on one (n,m) pair -> every wave-level load is 1KB contiguous.
__global__ __launch_bounds__(256)
void gate_kernel(const float* __restrict__ ef,
                 const float* __restrict__ we,
                 const float* __restrict__ be,
                 const float* __restrict__ sup1,
                 float* __restrict__ G) {
    const size_t tid  = (size_t)blockIdx.x * blockDim.x + threadIdx.x;
    const size_t pair = tid >> 2;          // (n*N + m)
    const int    sub  = (int)(threadIdx.x & 3);
    if (pair >= (size_t)N * N) return;

    const float4 e4 = *reinterpret_cast<const float4*>(ef + pair * E + sub * 4);
    const float4 w4 = *reinterpret_cast<const float4*>(we + pair * E + sub * 4);
    float v = e4.x * w4.x + e4.y * w4.y + e4.z * w4.z + e4.w * w4.w;
    v += __shfl_xor(v, 1);
    v += __shfl_xor(v, 2);
    if (sub == 0) {
        const float t = v + be[pair];
        const float g = 1.f / (1.f + expf(-t));
        G[pair] = g * sup1[pair];
    }
}

// Kernel 3: out[n,o] = relu( sum_m S0[n,m]*pre0[m,o] + G[n,m]*pre1[m,o] + b[o] )
#define BN 8
#define BM 32
__global__ __launch_bounds__(256)
void out_gemm(const float* __restrict__ S0,
              const float* __restrict__ G,
              const float* __restrict__ pre,   // [2][N][O]
              const float* __restrict__ bias,
              float* __restrict__ out) {
    __shared__ float p0s[BM][O];
    __shared__ float p1s[BM][O];
    __shared__ float s0t[BN][BM];
    __shared__ float gt[BN][BM];

    const float* __restrict__ pre0 = pre;
    const float* __restrict__ pre1 = pre + (size_t)N * O;

    const int tid = threadIdx.x;
    const int tx  = tid & 127;   // o
    const int ty  = tid >> 7;    // 0..1 (row group)
    const int n0  = blockIdx.x * BN;

    float acc[4] = {0.f, 0.f, 0.f, 0.f};

    for (int m0 = 0; m0 < N; m0 += BM) {
        // stage pre tiles [BM][O]
        for (int i = tid; i < BM * O; i += 256) {
            const int mr = i >> 7, oc = i & 127;
            p0s[mr][oc] = pre0[(size_t)(m0 + mr) * O + oc];
            p1s[mr][oc] = pre1[(size_t)(m0 + mr) * O + oc];
        }
        // stage adjacency tiles [BN][BM]
        if (tid < BN * BM) {
            const int r = tid >> 5, c = tid & 31;
            s0t[r][c] = S0[(size_t)(n0 + r) * N + m0 + c];
            gt[r][c]  = G [(size_t)(n0 + r) * N + m0 + c];
        }
        __syncthreads();

#pragma unroll
        for (int mm = 0; mm < BM; ++mm) {
            const float a0 = p0s[mm][tx];
            const float a1 = p1s[mm][tx];
#pragma unroll
            for (int r = 0; r < 4; ++r) {
                const int row = ty * 4 + r;
                acc[r] = fmaf(s0t[row][mm], a0, acc[r]);
                acc[r] = fmaf(gt[row][mm],  a1, acc[r]);
            }
        }
        __syncthreads();
    }

    const float bo = bias[tx];
#pragma unroll
    for (int r = 0; r < 4; ++r) {
        const float v = acc[r] + bo;
        out[(size_t)(n0 + ty * 4 + r) * O + tx] = fmaxf(v, 0.f);
    }
}

extern "C" void kernel_launch(void* const* d_in, const int* in_sizes, int n_in,
                              void* d_out, int out_size, void* d_ws, size_t ws_size,
                              hipStream_t stream) {
    const float* x   = (const float*)d_in[0];   // [N,F]
    const float* sup = (const float*)d_in[1];   // [2,N,N]
    const float* ef  = (const float*)d_in[2];   // [N,N,E]
    const float* we  = (const float*)d_in[3];   // [N,N,E]
    const float* be  = (const float*)d_in[4];   // [N,N]
    const float* w0  = (const float*)d_in[5];   // [F,O]
    const float* w1  = (const float*)d_in[6];   // [F,O]
    const float* b   = (const float*)d_in[7];   // [O]
    float* out = (float*)d_out;

    float* pre = (float*)d_ws;                      // [2][N][O]  (2 MB)
    float* G   = pre + 2 * (size_t)N * O;           // [N][N]     (16.8 MB)

    // 1. pre0/pre1
    pre_gemm<<<dim3(N, 2), 128, 0, stream>>>(x, w0, w1, pre);

    // 2. gated adjacency
    const size_t gate_threads = (size_t)N * N * 4;
    gate_kernel<<<(unsigned)(gate_threads / 256), 256, 0, stream>>>(
        ef, we, be, sup + (size_t)N * N, G);

    // 3. output GEMM + bias + relu
    out_gemm<<<N / BN, 256, 0, stream>>>(sup, G, pre, b, out);
}

// Round 2
// 161.425 us; speedup vs baseline: 2.0654x; 2.0654x over previous
//
#include <hip/hip_runtime.h>
#include <math.h>

#define N 2048
#define F 128
#define O 128
#define E 16

typedef __attribute__((ext_vector_type(8))) short    shortx8;
typedef __attribute__((ext_vector_type(8))) unsigned short u16x8;
typedef __attribute__((ext_vector_type(4))) float    floatx4;

static __device__ __forceinline__ unsigned short f2bf(float f) {
    unsigned int u = __float_as_uint(f);
    unsigned int r = (u + 0x7FFFu + ((u >> 16) & 1u)) >> 16;
    return (unsigned short)r;
}

// ---------------- Kernel 1: pre[b][n][o] = (x @ w_b)[n][o]  -> bf16 ----------------
__global__ __launch_bounds__(128)
void pre_gemm(const float* __restrict__ x,
              const float* __restrict__ w0,
              const float* __restrict__ w1,
              unsigned short* __restrict__ pre_bf) {
    const int n = blockIdx.x;
    const int b = blockIdx.y;
    const int o = threadIdx.x;
    const float* __restrict__ w = b ? w1 : w0;
    __shared__ float xs[F];
    xs[o] = x[(size_t)n * F + o];
    __syncthreads();
    float acc = 0.f;
#pragma unroll 8
    for (int k = 0; k < F; ++k)
        acc += xs[k] * w[(size_t)k * O + o];
    pre_bf[(size_t)b * N * O + (size_t)n * O + o] = f2bf(acc);
}

// ---------------- Kernel 2: preT[b][o][n] = pre[b][n][o]  (bf16 transpose) ----------
__global__ __launch_bounds__(256)
void transpose_pre(const unsigned short* __restrict__ pre_bf,
                   unsigned short* __restrict__ preT) {
    __shared__ unsigned short tile[64][65];
    const int n0 = blockIdx.x * 64, o0 = blockIdx.y * 64;
    const size_t base = (size_t)blockIdx.z * N * O;
    const int t = threadIdx.x;
    const int r = t >> 2, q = t & 3;
    const unsigned short* src = pre_bf + base + (size_t)(n0 + r) * O + o0 + q * 16;
    u16x8 v0 = *(const u16x8*)(src);
    u16x8 v1 = *(const u16x8*)(src + 8);
#pragma unroll
    for (int j = 0; j < 8; ++j) {
        tile[q * 16 + j][r]     = v0[j];
        tile[q * 16 + 8 + j][r] = v1[j];
    }
    __syncthreads();
    u16x8 w0v, w1v;
#pragma unroll
    for (int j = 0; j < 8; ++j) {
        w0v[j] = tile[r][q * 16 + j];
        w1v[j] = tile[r][q * 16 + 8 + j];
    }
    unsigned short* dst = preT + base + (size_t)(o0 + r) * N + n0 + q * 16;
    *(u16x8*)(dst)     = w0v;
    *(u16x8*)(dst + 8) = w1v;
}

// ---------------- Kernel 3: fused gate + dual-GEMM (split-K, MFMA bf16) -------------
// grid: 256 blocks = 64 rowblocks(BN=32) x 4 kchunks(MK=512); 512 threads (8 waves).
// partial[kc][n][o] += sum over m-chunk of ( S0[n,m]*pre0[m,o] + G[n,m]*pre1[m,o] )
#define BN 32
#define MK 512
#define BK 32
#define BPAD 48   // padded row stride (in u16) for B tiles

__global__ __launch_bounds__(512)
void fused_gemm(const float* __restrict__ sup,
                const float* __restrict__ ef,
                const float* __restrict__ we,
                const float* __restrict__ be,
                const unsigned short* __restrict__ preT,
                float* __restrict__ partial) {
    __shared__ unsigned short s0A[BN * BK];      // 2 KB
    __shared__ unsigned short gA [BN * BK];      // 2 KB
    __shared__ unsigned short B0 [O * BPAD];     // 12 KB
    __shared__ unsigned short B1 [O * BPAD];     // 12 KB

    const int tid = threadIdx.x;
    const int bx  = blockIdx.x;
    const int rb  = bx & 63;
    const int kc  = bx >> 6;
    const int n0      = rb * BN;
    const int m_base  = kc * MK;

    const float* __restrict__ S0   = sup;
    const float* __restrict__ sup1 = sup + (size_t)N * N;

    const int lane = tid & 63;
    const int wid  = tid >> 6;     // 0..7
    const int wrow = wid >> 2;     // 0..1  (16-row group)
    const int wcol = wid & 3;      // 0..3  (32-col group)

    // staging pair mapping: pairs p = tid and tid+512 of the 32x32 tile
    const int nn0 = tid >> 5;      // 0..15
    const int mm0 = tid & 31;      // 0..31
    // B staging mapping
    const int bo = tid >> 2;       // 0..127
    const int bq = tid & 3;        // 0..3

    floatx4 acc0 = {0.f, 0.f, 0.f, 0.f};
    floatx4 acc1 = {0.f, 0.f, 0.f, 0.f};

    for (int step = 0; step < MK / BK; ++step) {
        const int m0 = m_base + step * BK;

        // ---- stage B tiles: preT[b][o][m0..m0+32) -> LDS [o][BPAD]
        {
            const size_t src = (size_t)bo * N + (size_t)(m0 + bq * 8);
            u16x8 v0 = *(const u16x8*)(preT + src);
            u16x8 v1 = *(const u16x8*)(preT + (size_t)O * N + src);
            *(u16x8*)(B0 + bo * BPAD + bq * 8) = v0;
            *(u16x8*)(B1 + bo * BPAD + bq * 8) = v1;
        }

        // ---- gate compute + A tiles (2 pairs per thread)
#pragma unroll
        for (int rep = 0; rep < 2; ++rep) {
            const int nn = nn0 + rep * 16;
            const size_t pix = (size_t)(n0 + nn) * N + (size_t)(m0 + mm0);
            const float4* e4 = (const float4*)(ef + pix * E);
            const float4* w4 = (const float4*)(we + pix * E);
            float v = 0.f;
#pragma unroll
            for (int j = 0; j < 4; ++j) {
                const float4 a = e4[j], b = w4[j];
                v += a.x * b.x + a.y * b.y + a.z * b.z + a.w * b.w;
            }
            const float tt = v + be[pix];
            const float g  = (1.f / (1.f + __expf(-tt))) * sup1[pix];
            gA [nn * BK + mm0] = f2bf(g);
            s0A[nn * BK + mm0] = f2bf(S0[pix]);
        }
        __syncthreads();

        // ---- MFMA: acc += A_s0 . B0  +  A_g . B1
        {
            const int arow = wrow * 16 + (lane & 15);
            const int kg   = lane >> 4;
            const shortx8 a_s = *(const shortx8*)(s0A + arow * BK + kg * 8);
            const shortx8 a_g = *(const shortx8*)(gA  + arow * BK + kg * 8);
            const int col0 = wcol * 32 + (lane & 15);
            const shortx8 b00 = *(const shortx8*)(B0 + col0 * BPAD + kg * 8);
            const shortx8 b10 = *(const shortx8*)(B1 + col0 * BPAD + kg * 8);
            const shortx8 b01 = *(const shortx8*)(B0 + (col0 + 16) * BPAD + kg * 8);
            const shortx8 b11 = *(const shortx8*)(B1 + (col0 + 16) * BPAD + kg * 8);
            acc0 = __builtin_amdgcn_mfma_f32_16x16x32_bf16(a_s, b00, acc0, 0, 0, 0);
            acc0 = __builtin_amdgcn_mfma_f32_16x16x32_bf16(a_g, b10, acc0, 0, 0, 0);
            acc1 = __builtin_amdgcn_mfma_f32_16x16x32_bf16(a_s, b01, acc1, 0, 0, 0);
            acc1 = __builtin_amdgcn_mfma_f32_16x16x32_bf16(a_g, b11, acc1, 0, 0, 0);
        }
        __syncthreads();
    }

    // ---- write partial [kc][n][o]; C/D: col = lane&15, row = (lane>>4)*4 + j
    const int prow = (lane >> 4) * 4;
    const int pcol = wcol * 32 + (lane & 15);
    float* dst = partial + (size_t)kc * (N * O)
               + (size_t)(n0 + wrow * 16 + prow) * O + pcol;
#pragma unroll
    for (int j = 0; j < 4; ++j) {
        dst[(size_t)j * O]      = acc0[j];
        dst[(size_t)j * O + 16] = acc1[j];
    }
}

// ---------------- Kernel 4: out = relu(sum_kc partial + bias) -----------------------
__global__ __launch_bounds__(256)
void reduce_out(const float* __restrict__ partial,
                const float* __restrict__ bias,
                float* __restrict__ out) {
    const int i4 = blockIdx.x * 256 + threadIdx.x;   // 0..65535 (float4 index)
    const float4* p = (const float4*)partial;
    const float4 a = p[i4];
    const float4 b = p[i4 + 65536];
    const float4 c = p[i4 + 2 * 65536];
    const float4 d = p[i4 + 3 * 65536];
    const float4 bb = ((const float4*)bias)[i4 & 31];
    float4 r;
    r.x = fmaxf(a.x + b.x + c.x + d.x + bb.x, 0.f);
    r.y = fmaxf(a.y + b.y + c.y + d.y + bb.y, 0.f);
    r.z = fmaxf(a.z + b.z + c.z + d.z + bb.z, 0.f);
    r.w = fmaxf(a.w + b.w + c.w + d.w + bb.w, 0.f);
    ((float4*)out)[i4] = r;
}

extern "C" void kernel_launch(void* const* d_in, const int* in_sizes, int n_in,
                              void* d_out, int out_size, void* d_ws, size_t ws_size,
                              hipStream_t stream) {
    const float* x   = (const float*)d_in[0];   // [N,F]
    const float* sup = (const float*)d_in[1];   // [2,N,N]
    const float* ef  = (const float*)d_in[2];   // [N,N,E]
    const float* we  = (const float*)d_in[3];   // [N,N,E]
    const float* be  = (const float*)d_in[4];   // [N,N]
    const float* w0  = (const float*)d_in[5];   // [F,O]
    const float* w1  = (const float*)d_in[6];   // [F,O]
    const float* b   = (const float*)d_in[7];   // [O]
    float* out = (float*)d_out;

    unsigned short* pre_bf = (unsigned short*)d_ws;       // [2][N][O] bf16, 1 MB
    unsigned short* preT   = pre_bf + 2 * (size_t)N * O;  // [2][O][N] bf16, 1 MB
    float* partial = (float*)(preT + 2 * (size_t)N * O);  // [4][N][O] f32,  4 MB

    pre_gemm<<<dim3(N, 2), 128, 0, stream>>>(x, w0, w1, pre_bf);
    transpose_pre<<<dim3(N / 64, O / 64, 2), 256, 0, stream>>>(pre_bf, preT);
    fused_gemm<<<256, 512, 0, stream>>>(sup, ef, we, be, preT, partial);
    reduce_out<<<256, 256, 0, stream>>>(partial, b, out);
}

// Round 3
// 148.569 us; speedup vs baseline: 2.2442x; 1.0865x over previous
//
#include <hip/hip_runtime.h>
#include <math.h>

#define N 2048
#define F 128
#define O 128
#define E 16

#define BN 32
#define BK 32
#define KC 8
#define MK (N / KC)        // 256
#define STEPS (MK / BK)    // 8
#define APAD 40            // u16 row stride, 80B -> conflict-free bank walk
#define BPAD 40

typedef __attribute__((ext_vector_type(8))) short          shortx8;
typedef __attribute__((ext_vector_type(8))) unsigned short u16x8;
typedef __attribute__((ext_vector_type(4))) float          floatx4;

static __device__ __forceinline__ unsigned short f2bf(float f) {
    unsigned int u = __float_as_uint(f);
    unsigned int r = (u + 0x7FFFu + ((u >> 16) & 1u)) >> 16;
    return (unsigned short)r;
}

// ---------------- Kernel 1: pre[b][n][o] = (x @ w_b)[n][o]  -> bf16 ----------------
__global__ __launch_bounds__(128)
void pre_gemm(const float* __restrict__ x,
              const float* __restrict__ w0,
              const float* __restrict__ w1,
              unsigned short* __restrict__ pre_bf) {
    const int n = blockIdx.x;
    const int b = blockIdx.y;
    const int o = threadIdx.x;
    const float* __restrict__ w = b ? w1 : w0;
    __shared__ float xs[F];
    xs[o] = x[(size_t)n * F + o];
    __syncthreads();
    float acc = 0.f;
#pragma unroll 8
    for (int k = 0; k < F; ++k)
        acc += xs[k] * w[(size_t)k * O + o];
    pre_bf[(size_t)b * N * O + (size_t)n * O + o] = f2bf(acc);
}

// ---------------- Kernel 2: preT[b][o][n] = pre[b][n][o]  (bf16 transpose) ----------
__global__ __launch_bounds__(256)
void transpose_pre(const unsigned short* __restrict__ pre_bf,
                   unsigned short* __restrict__ preT) {
    __shared__ unsigned short tile[64][65];
    const int n0 = blockIdx.x * 64, o0 = blockIdx.y * 64;
    const size_t base = (size_t)blockIdx.z * N * O;
    const int t = threadIdx.x;
    const int r = t >> 2, q = t & 3;
    const unsigned short* src = pre_bf + base + (size_t)(n0 + r) * O + o0 + q * 16;
    u16x8 v0 = *(const u16x8*)(src);
    u16x8 v1 = *(const u16x8*)(src + 8);
#pragma unroll
    for (int j = 0; j < 8; ++j) {
        tile[q * 16 + j][r]     = v0[j];
        tile[q * 16 + 8 + j][r] = v1[j];
    }
    __syncthreads();
    u16x8 w0v, w1v;
#pragma unroll
    for (int j = 0; j < 8; ++j) {
        w0v[j] = tile[r][q * 16 + j];
        w1v[j] = tile[r][q * 16 + 8 + j];
    }
    unsigned short* dst = preT + base + (size_t)(o0 + r) * N + n0 + q * 16;
    *(u16x8*)(dst)     = w0v;
    *(u16x8*)(dst + 8) = w1v;
}

// ---------------- Kernel 3: fused gate + dual-GEMM, pipelined ----------------------
// grid: 512 blocks = 64 rowblocks(BN=32) x 8 kchunks(MK=256); 512 threads (8 waves).
// One-step register prefetch + LDS double buffer + single barrier per K-step.

struct Pref {
    float4 e0[4], e1[4], w0[4], w1[4];   // ef/we for the thread's 2 pairs
    float  be0, be1, s00, s01, s10, s11; // bias_edge, support0, support1
    u16x8  bv0, bv1;                     // B tile slices (preT)
};

__device__ __forceinline__ void load_step(
    const float* __restrict__ ef, const float* __restrict__ we,
    const float* __restrict__ be, const float* __restrict__ S0,
    const float* __restrict__ sup1, const unsigned short* __restrict__ preT,
    size_t pix0, size_t sbase, int m0, Pref& P)
{
    const size_t pixA = pix0 + (size_t)m0;
    const size_t pixB = pixA + (size_t)16 * N;
    const float4* eA = (const float4*)(ef + pixA * E);
    const float4* wA = (const float4*)(we + pixA * E);
    const float4* eB = (const float4*)(ef + pixB * E);
    const float4* wB = (const float4*)(we + pixB * E);
#pragma unroll
    for (int j = 0; j < 4; ++j) {
        P.e0[j] = eA[j]; P.w0[j] = wA[j];
        P.e1[j] = eB[j]; P.w1[j] = wB[j];
    }
    P.be0 = be[pixA]; P.s00 = S0[pixA]; P.s10 = sup1[pixA];
    P.be1 = be[pixB]; P.s01 = S0[pixB]; P.s11 = sup1[pixB];
    const size_t src = sbase + (size_t)m0;
    P.bv0 = *(const u16x8*)(preT + src);
    P.bv1 = *(const u16x8*)(preT + (size_t)O * N + src);
}

__device__ __forceinline__ void produce(
    const Pref& P, int nn0, int mm0, int bo, int bq,
    unsigned short* aS, unsigned short* aG,
    unsigned short* B0, unsigned short* B1)
{
    float v0 = 0.f, v1 = 0.f;
#pragma unroll
    for (int j = 0; j < 4; ++j) {
        v0 += P.e0[j].x * P.w0[j].x + P.e0[j].y * P.w0[j].y
            + P.e0[j].z * P.w0[j].z + P.e0[j].w * P.w0[j].w;
        v1 += P.e1[j].x * P.w1[j].x + P.e1[j].y * P.w1[j].y
            + P.e1[j].z * P.w1[j].z + P.e1[j].w * P.w1[j].w;
    }
    const float g0 = (1.f / (1.f + __expf(-(v0 + P.be0)))) * P.s10;
    const float g1 = (1.f / (1.f + __expf(-(v1 + P.be1)))) * P.s11;
    aG[nn0 * APAD + mm0]        = f2bf(g0);
    aG[(nn0 + 16) * APAD + mm0] = f2bf(g1);
    aS[nn0 * APAD + mm0]        = f2bf(P.s00);
    aS[(nn0 + 16) * APAD + mm0] = f2bf(P.s01);
    *(u16x8*)(B0 + bo * BPAD + bq * 8) = P.bv0;
    *(u16x8*)(B1 + bo * BPAD + bq * 8) = P.bv1;
}

__device__ __forceinline__ void mfma_step(
    const unsigned short* aS, const unsigned short* aG,
    const unsigned short* B0, const unsigned short* B1,
    int arow, int kg, int col0, floatx4& acc0, floatx4& acc1)
{
    const shortx8 a_s = *(const shortx8*)(aS + arow * APAD + kg * 8);
    const shortx8 a_g = *(const shortx8*)(aG + arow * APAD + kg * 8);
    const shortx8 b00 = *(const shortx8*)(B0 + col0 * BPAD + kg * 8);
    const shortx8 b10 = *(const shortx8*)(B1 + col0 * BPAD + kg * 8);
    const shortx8 b01 = *(const shortx8*)(B0 + (col0 + 16) * BPAD + kg * 8);
    const shortx8 b11 = *(const shortx8*)(B1 + (col0 + 16) * BPAD + kg * 8);
    acc0 = __builtin_amdgcn_mfma_f32_16x16x32_bf16(a_s, b00, acc0, 0, 0, 0);
    acc0 = __builtin_amdgcn_mfma_f32_16x16x32_bf16(a_g, b10, acc0, 0, 0, 0);
    acc1 = __builtin_amdgcn_mfma_f32_16x16x32_bf16(a_s, b01, acc1, 0, 0, 0);
    acc1 = __builtin_amdgcn_mfma_f32_16x16x32_bf16(a_g, b11, acc1, 0, 0, 0);
}

__global__ __launch_bounds__(512, 4)
void fused_gemm(const float* __restrict__ sup,
                const float* __restrict__ ef,
                const float* __restrict__ we,
                const float* __restrict__ be,
                const unsigned short* __restrict__ preT,
                float* __restrict__ partial) {
    __shared__ unsigned short aS0[BN * APAD], aG0[BN * APAD];
    __shared__ unsigned short B00[O * BPAD],  B10[O * BPAD];
    __shared__ unsigned short aS1[BN * APAD], aG1[BN * APAD];
    __shared__ unsigned short B01[O * BPAD],  B11[O * BPAD];

    const int tid = threadIdx.x;
    const int bx  = blockIdx.x;
    const int rb  = bx & 63;
    const int kc  = bx >> 6;
    const int n0     = rb * BN;
    const int m_base = kc * MK;

    const float* __restrict__ S0   = sup;
    const float* __restrict__ sup1 = sup + (size_t)N * N;

    const int lane = tid & 63;
    const int wid  = tid >> 6;     // 0..7
    const int wrow = wid >> 2;     // 0..1
    const int wcol = wid & 3;      // 0..3

    const int nn0 = tid >> 5;      // 0..15 (pair row within tile)
    const int mm0 = tid & 31;      // 0..31 (pair col within tile)
    const int bo  = tid >> 2;      // 0..127
    const int bq  = tid & 3;       // 0..3

    const size_t pix0  = (size_t)(n0 + nn0) * N + (size_t)(m_base + mm0);
    const size_t sbase = (size_t)bo * N + (size_t)(m_base + bq * 8);

    const int arow = wrow * 16 + (lane & 15);
    const int kg   = lane >> 4;
    const int col0 = wcol * 32 + (lane & 15);

    floatx4 acc0 = {0.f, 0.f, 0.f, 0.f};
    floatx4 acc1 = {0.f, 0.f, 0.f, 0.f};

    Pref P;
    // prologue: step 0 -> buf0; prefetch step 1
    load_step(ef, we, be, S0, sup1, preT, pix0, sbase, 0, P);
    produce(P, nn0, mm0, bo, bq, aS0, aG0, B00, B10);
    load_step(ef, we, be, S0, sup1, preT, pix0, sbase, BK, P);
    __syncthreads();

#pragma unroll 1
    for (int s = 0; s < STEPS; s += 2) {
        // even half: produce step s+1 -> buf1; prefetch s+2; mfma buf0
        produce(P, nn0, mm0, bo, bq, aS1, aG1, B01, B11);
        if (s + 2 < STEPS)
            load_step(ef, we, be, S0, sup1, preT, pix0, sbase, (s + 2) * BK, P);
        mfma_step(aS0, aG0, B00, B10, arow, kg, col0, acc0, acc1);
        __syncthreads();
        // odd half: produce step s+2 -> buf0; prefetch s+3; mfma buf1
        if (s + 2 < STEPS) {
            produce(P, nn0, mm0, bo, bq, aS0, aG0, B00, B10);
            if (s + 3 < STEPS)
                load_step(ef, we, be, S0, sup1, preT, pix0, sbase, (s + 3) * BK, P);
        }
        mfma_step(aS1, aG1, B01, B11, arow, kg, col0, acc0, acc1);
        __syncthreads();
    }

    // C/D layout: col = lane&15, row = (lane>>4)*4 + j  (m89-verified)
    const int prow = (lane >> 4) * 4;
    const int pcol = wcol * 32 + (lane & 15);
    float* dst = partial + (size_t)kc * (N * O)
               + (size_t)(n0 + wrow * 16 + prow) * O + pcol;
#pragma unroll
    for (int j = 0; j < 4; ++j) {
        dst[(size_t)j * O]      = acc0[j];
        dst[(size_t)j * O + 16] = acc1[j];
    }
}

// ---------------- Kernel 4: out = relu(sum_kc partial + bias) -----------------------
__global__ __launch_bounds__(256)
void reduce_out(const float* __restrict__ partial,
                const float* __restrict__ bias,
                float* __restrict__ out) {
    const int i4 = blockIdx.x * 256 + threadIdx.x;   // 0..65535 (float4 index)
    const float4* p = (const float4*)partial;
    float4 r = p[i4];
#pragma unroll
    for (int j = 1; j < KC; ++j) {
        const float4 a = p[i4 + (size_t)j * 65536];
        r.x += a.x; r.y += a.y; r.z += a.z; r.w += a.w;
    }
    const float4 bb = ((const float4*)bias)[i4 & 31];
    float4 o;
    o.x = fmaxf(r.x + bb.x, 0.f);
    o.y = fmaxf(r.y + bb.y, 0.f);
    o.z = fmaxf(r.z + bb.z, 0.f);
    o.w = fmaxf(r.w + bb.w, 0.f);
    ((float4*)out)[i4] = o;
}

extern "C" void kernel_launch(void* const* d_in, const int* in_sizes, int n_in,
                              void* d_out, int out_size, void* d_ws, size_t ws_size,
                              hipStream_t stream) {
    const float* x   = (const float*)d_in[0];   // [N,F]
    const float* sup = (const float*)d_in[1];   // [2,N,N]
    const float* ef  = (const float*)d_in[2];   // [N,N,E]
    const float* we  = (const float*)d_in[3];   // [N,N,E]
    const float* be  = (const float*)d_in[4];   // [N,N]
    const float* w0  = (const float*)d_in[5];   // [F,O]
    const float* w1  = (const float*)d_in[6];   // [F,O]
    const float* b   = (const float*)d_in[7];   // [O]
    float* out = (float*)d_out;

    unsigned short* pre_bf = (unsigned short*)d_ws;       // [2][N][O] bf16, 1 MB
    unsigned short* preT   = pre_bf + 2 * (size_t)N * O;  // [2][O][N] bf16, 1 MB
    float* partial = (float*)(preT + 2 * (size_t)N * O);  // [KC][N][O] f32, 8 MB

    pre_gemm<<<dim3(N, 2), 128, 0, stream>>>(x, w0, w1, pre_bf);
    transpose_pre<<<dim3(N / 64, O / 64, 2), 256, 0, stream>>>(pre_bf, preT);
    fused_gemm<<<KC * 64, 512, 0, stream>>>(sup, ef, we, be, preT, partial);
    reduce_out<<<256, 256, 0, stream>>>(partial, b, out);
}